// Round 8
// baseline (152.292 us; speedup 1.0000x reference)
//
#include <hip/hip_runtime.h>

// ---------------------------------------------------------------------------
// MultiHeadAttention: x(2,2048,768) -> QKV proj -> 12-head causal attn -> proj
// Round 19: merged-prefix pair attn + GEMM revert. R7 facts: (a) 2-phase
// K32 GEMMs regressed +3.6 -> reverted to R6 1-phase K64 form; (b) attn=43.5us
// (stable across 4 rewrites), no pipe saturated -> cut ITERATIONS, not pipes.
// Pair job (tl=j, th=63-j): light KV range [0,nktl) is a PREFIX of heavy
// [0,nkth) (nktl<=8<9<=nkth, nktl+nkth=17). Merge: stream each tile ONCE
// (nkth iters, avg 12.5 vs 17 = -26% stages/barriers/drains); while kt<nktl
// compute BOTH q-tiles from the same staged tile, sharing the ak/bv LDS
// fragments (joint-phase LDS reads halved per computed tile). Compute stays
// exactly 17 tile-computations/job. Combine epilogue (R6) runs twice.
// prep/gemm1/gemm2 byte-identical to R6/R14.
// ---------------------------------------------------------------------------

typedef float f32x4 __attribute__((ext_vector_type(4)));
typedef __bf16 bf16x8 __attribute__((ext_vector_type(8)));
typedef unsigned int u32x4 __attribute__((ext_vector_type(4)));

#define D_MODEL 768
#define F3 2304
#define NHEADS 12
#define HEAD 64
#define BB 2
#define TT 2048
#define MROWS (BB*TT)      // 4096
#define KDIM 768
#define LOG2E 1.44269504f
#define NX (MROWS*D_MODEL)
#define NW1 (F3*KDIM)
#define NW2 (D_MODEL*KDIM)

__device__ __forceinline__ unsigned short f2bf(float f) {
    unsigned int u = __float_as_uint(f);
    u += 0x7fffu + ((u >> 16) & 1u);
    return (unsigned short)(u >> 16);
}
__device__ __forceinline__ unsigned int pack2bf(float a, float b) {
    unsigned int ua = __float_as_uint(a), ub = __float_as_uint(b);
    ua += 0x7fffu + ((ua >> 16) & 1u);
    ub += 0x7fffu + ((ub >> 16) & 1u);
    return (ua >> 16) | (ub & 0xffff0000u);
}

__device__ __forceinline__ void async_copy16(unsigned short* lds, const unsigned short* g) {
    __builtin_amdgcn_global_load_lds(
        (const __attribute__((address_space(1))) unsigned int*)(const void*)g,
        (__attribute__((address_space(3))) unsigned int*)(void*)lds,
        16, 0, 0);
}

// ---- fused prep: fp32 -> bf16 for x, W1, W2 (4 elems/thread) --------------
__global__ void prep(const float* __restrict__ x, const float* __restrict__ W1,
                     const float* __restrict__ W2, unsigned short* __restrict__ xb,
                     unsigned short* __restrict__ w1b, unsigned short* __restrict__ w2b) {
    const int i4 = (blockIdx.x * blockDim.x + threadIdx.x) * 4;
    const float* src; unsigned short* dst; int off;
    if (i4 < NX)                  { src = x;  dst = xb;  off = i4; }
    else if (i4 < NX + NW1)       { src = W1; dst = w1b; off = i4 - NX; }
    else if (i4 < NX + NW1 + NW2) { src = W2; dst = w2b; off = i4 - NX - NW1; }
    else return;
    float4 v = *(const float4*)(src + off);
    uint2 o;
    o.x = pack2bf(v.x, v.y);
    o.y = pack2bf(v.z, v.w);
    *(uint2*)(dst + off) = o;
}

// ---- GEMM1: 128x96 tile, 768 blocks = 3/CU exact. C = A Bw^T --------------
// XCD band swizzle: xcd = F&7 owns an 8(m) x 12(n) tile band.
__global__ __launch_bounds__(256, 4) void gemm1(
    const unsigned short* __restrict__ A, const unsigned short* __restrict__ Bw,
    const float* __restrict__ bias, int K,
    unsigned short* __restrict__ Qb, unsigned short* __restrict__ Kb,
    unsigned short* __restrict__ VT)
{
    __shared__ unsigned short As[128*64];    // 16 KB
    __shared__ unsigned short Bs[96*64];     // 12 KB
    const int tid  = threadIdx.x;
    const int wave = tid >> 6;
    const int lane = tid & 63;
    const int quad = lane >> 4;
    const int l16  = lane & 15;

    const int F   = blockIdx.x;
    const int xcd = F & 7;
    const int idx = F >> 3;                  // 0..95
    const int bm  = (xcd & 3) * 8 + (idx & 7);    // 0..31
    const int bn  = (xcd >> 2) * 12 + (idx >> 3); // 0..23
    const int m0  = bm * 128;
    const int n0  = bn * 96;
    const int seg = bn >> 3;                 // 0=Q 1=K 2=V (96*8=768)

    const int wm = (wave >> 1) * 64;
    const int wn = (wave & 1) * 48;

    f32x4 acc[4][3] = {};

    const unsigned short* Ablk = A + (size_t)m0 * K;
    const unsigned short* Bblk = Bw + (size_t)n0 * K;
    const int srow = tid >> 3;                            // 0..31
    const int scol = ((tid & 7) ^ (srow & 7)) * 8;        // swizzled source chunk

    for (int k0 = 0; k0 < K; k0 += 64) {
        #pragma unroll
        for (int r = 0; r < 4; ++r)      // A rows r*32 + srow (128 rows)
            async_copy16(As + r*2048 + tid*8,
                         Ablk + (size_t)(r*32 + srow) * K + k0 + scol);
        #pragma unroll
        for (int r = 0; r < 3; ++r)      // B rows r*32 + srow (96 rows)
            async_copy16(Bs + r*2048 + tid*8,
                         Bblk + (size_t)(r*32 + srow) * K + k0 + scol);
        asm volatile("s_waitcnt vmcnt(0)" ::: "memory");
        __syncthreads();

        #pragma unroll
        for (int kc2 = 0; kc2 < 2; ++kc2) {
            const int pos = ((kc2*4 + quad) ^ (l16 & 7)) * 8;   // swizzled read
            bf16x8 a[4], b[3];
            #pragma unroll
            for (int i = 0; i < 4; ++i)
                a[i] = *(const bf16x8*)(As + (wm + i*16 + l16)*64 + pos);
            #pragma unroll
            for (int j = 0; j < 3; ++j)
                b[j] = *(const bf16x8*)(Bs + (wn + j*16 + l16)*64 + pos);
            #pragma unroll
            for (int i = 0; i < 4; ++i)
                #pragma unroll
                for (int j = 0; j < 3; ++j)
                    acc[i][j] = __builtin_amdgcn_mfma_f32_16x16x32_bf16(a[i], b[j], acc[i][j], 0, 0, 0);
        }
        __syncthreads();
    }

    if (seg < 2) {                           // Q or K: (b,h,t,d) scalar stores
        #pragma unroll
        for (int j = 0; j < 3; ++j) {
            const int n = n0 + wn + j*16 + l16;
            const float bv = bias[n];
            const int f = n - seg * 768;
            const int h = f >> 6, d = f & 63;
            #pragma unroll
            for (int i = 0; i < 4; ++i)
                #pragma unroll
                for (int r = 0; r < 4; ++r) {
                    const int m = m0 + wm + i*16 + quad*4 + r;
                    const int b = m >> 11, t = m & 2047;
                    const size_t idxq = (((size_t)(b*NHEADS + h)) * TT + t) * HEAD + d;
                    const float v = acc[i][j][r] + bv;
                    if (seg == 0) Qb[idxq] = f2bf(v * (0.125f * LOG2E));
                    else          Kb[idxq] = f2bf(v);
                }
        }
    } else {                                 // V: write V^T (b,h,d,t), 8B packed
        #pragma unroll
        for (int j = 0; j < 3; ++j) {
            const int n = n0 + wn + j*16 + l16;
            const float bv = bias[n];
            const int f = n - 1536;
            const int h = f >> 6, d = f & 63;
            #pragma unroll
            for (int i = 0; i < 4; ++i) {
                const int m = m0 + wm + i*16 + quad*4;
                const int b = m >> 11, t = m & 2047;
                uint2 pk;
                pk.x = pack2bf(acc[i][j][0] + bv, acc[i][j][1] + bv);
                pk.y = pack2bf(acc[i][j][2] + bv, acc[i][j][3] + bv);
                *(uint2*)(VT + ((size_t)(b*NHEADS + h) * HEAD + d) * TT + t) = pk;
            }
        }
    }
}

// ---- GEMM2: 64x96 tile, 512 blocks = 2/CU exact. fp32 out + bias ----------
// XCD band swizzle: xcd owns a 16(m) x 4(n) tile band.
__global__ __launch_bounds__(256, 4) void gemm2(
    const unsigned short* __restrict__ A, const unsigned short* __restrict__ Bw,
    const float* __restrict__ bias, int K, float* __restrict__ Cout)
{
    __shared__ unsigned short As[64*64];     // 8 KB
    __shared__ unsigned short Bs[96*64];     // 12 KB
    const int tid  = threadIdx.x;
    const int wave = tid >> 6;
    const int lane = tid & 63;
    const int quad = lane >> 4;
    const int l16  = lane & 15;

    const int F   = blockIdx.x;
    const int xcd = F & 7;
    const int idx = F >> 3;                  // 0..63
    const int m0  = ((xcd & 3) * 16 + (idx & 15)) * 64;   // 64 m-tiles
    const int n0  = ((xcd >> 2) * 4 + (idx >> 4)) * 96;   // 8 n-tiles

    const int wm = (wave >> 1) * 32;
    const int wn = (wave & 1) * 48;

    f32x4 acc[2][3] = {};

    const unsigned short* Ablk = A + (size_t)m0 * K;
    const unsigned short* Bblk = Bw + (size_t)n0 * K;
    const int srow = tid >> 3;                            // 0..31
    const int scol = ((tid & 7) ^ (srow & 7)) * 8;        // swizzled source chunk

    for (int k0 = 0; k0 < K; k0 += 64) {
        #pragma unroll
        for (int r = 0; r < 2; ++r)      // A rows r*32 + srow (64 rows)
            async_copy16(As + r*2048 + tid*8,
                         Ablk + (size_t)(r*32 + srow) * K + k0 + scol);
        #pragma unroll
        for (int r = 0; r < 3; ++r)      // B rows r*32 + srow (96 rows)
            async_copy16(Bs + r*2048 + tid*8,
                         Bblk + (size_t)(r*32 + srow) * K + k0 + scol);
        asm volatile("s_waitcnt vmcnt(0)" ::: "memory");
        __syncthreads();

        #pragma unroll
        for (int kc2 = 0; kc2 < 2; ++kc2) {
            const int pos = ((kc2*4 + quad) ^ (l16 & 7)) * 8;
            bf16x8 a[2], b[3];
            #pragma unroll
            for (int i = 0; i < 2; ++i)
                a[i] = *(const bf16x8*)(As + (wm + i*16 + l16)*64 + pos);
            #pragma unroll
            for (int j = 0; j < 3; ++j)
                b[j] = *(const bf16x8*)(Bs + (wn + j*16 + l16)*64 + pos);
            #pragma unroll
            for (int i = 0; i < 2; ++i)
                #pragma unroll
                for (int j = 0; j < 3; ++j)
                    acc[i][j] = __builtin_amdgcn_mfma_f32_16x16x32_bf16(a[i], b[j], acc[i][j], 0, 0, 0);
        }
        __syncthreads();
    }

    #pragma unroll
    for (int j = 0; j < 3; ++j) {
        const int n = n0 + wn + j*16 + l16;
        const float bv = bias[n];
        #pragma unroll
        for (int i = 0; i < 2; ++i)
            #pragma unroll
            for (int r = 0; r < 4; ++r) {
                const int m = m0 + wm + i*16 + quad*4 + r;
                Cout[(size_t)m * D_MODEL + n] = acc[i][j][r] + bv;
            }
    }
}

// ---- flash attention (causal), merged-prefix pair jobs, k-split waves -----
// 768 blocks (XCD owns 3 heads), 32 KB LDS -> 3/CU. Job j (0..31): light
// tile tl=j, heavy th=63-j. nktl=(j>>2)+1 (1..8), nkth=17-nktl (9..16).
// ONE streaming loop over kt in [0,nkth): stage K/V once; compute heavy
// always; compute light too while kt<nktl (sharing ak/bv fragments).
// Diag masks at kt==nktl-1 (light) / kt==nkth-1 (heavy). Two combines.
__global__ __launch_bounds__(256, 3) void attn(
    const unsigned short* __restrict__ Qb, const unsigned short* __restrict__ Kb,
    const unsigned short* __restrict__ VT, unsigned short* __restrict__ Ob)
{
    __shared__ unsigned short Ks[128*64];   // 16 KB (combine: waves 1,2 O-buf)
    __shared__ unsigned short Vt[64*128];   // 16 KB (combine: wave 3 O-buf + l)

    const int tid  = threadIdx.x;
    const int wave = tid >> 6;
    const int lane = tid & 63;
    const int quad = lane >> 4;
    const int l16  = lane & 15;

    const int F    = blockIdx.y * 32 + blockIdx.x;   // flat dispatch id
    const int xcd  = F & 7;
    const int slot = F >> 3;                          // 0..95
    const int bh   = xcd * 3 + (slot >> 5);           // 3 heads per XCD
    const int j    = slot & 31;                       // pair-job id 0..31
    const size_t hbase = (size_t)bh * TT * HEAD;

    const int nktl = (j >> 2) + 1;          // light KV tiles (1..8)
    const int nkth = 17 - nktl;             // heavy KV tiles (9..16)
    const int q0l  = j * 32;
    const int q0h  = (63 - j) * 32;

    // DMA source offsets (thread tid fills LDS chunk tid*8):
    const int krow = tid >> 3;
    const int kchunk = ((tid & 7) ^ (krow & 7)) * 8;
    const int vrow = tid >> 4;
    const int vchunk = ((tid & 15) ^ vrow) * 8;

    // Q B-frags for both tiles: [qs][kc2], lane l16 = q col
    bf16x8 qregl[2][2], qregh[2][2];
    #pragma unroll
    for (int qs = 0; qs < 2; ++qs) {
        const unsigned short* ql = Qb + hbase + (size_t)(q0l + qs*16 + l16) * HEAD + quad*8;
        const unsigned short* qh = Qb + hbase + (size_t)(q0h + qs*16 + l16) * HEAD + quad*8;
        qregl[qs][0] = *(const bf16x8*)(ql);
        qregl[qs][1] = *(const bf16x8*)(ql + 32);
        qregh[qs][0] = *(const bf16x8*)(qh);
        qregh[qs][1] = *(const bf16x8*)(qh + 32);
    }

    f32x4 oaccl[2][4] = {}, oacch[2][4] = {};   // [qs][dt]
    float lstl[2] = {0.f, 0.f}, lsth[2] = {0.f, 0.f};

    const int g1 = wave*4 + (quad >> 1);

    // per-tile compute: shared ak/bv fragments; QREG/OACC/LST/Q0 per tile
    #define TILE_COMPUTE(QREG, OACC, LST, Q0, DOMASK, KT)                       \
    do {                                                                        \
        f32x4 s[2][2] = {};                                                     \
        _Pragma("unroll")                                                       \
        for (int kc2 = 0; kc2 < 2; ++kc2)                                       \
            _Pragma("unroll")                                                   \
            for (int n = 0; n < 2; ++n)                                         \
                _Pragma("unroll")                                               \
                for (int qs = 0; qs < 2; ++qs)                                  \
                    s[n][qs] = __builtin_amdgcn_mfma_f32_16x16x32_bf16(         \
                        ak[kc2][n], QREG[qs][kc2], s[n][qs], 0, 0, 0);          \
        if (DOMASK) {                                                           \
            const int kq = (KT)*128 + wave*32 + quad*4;                         \
            _Pragma("unroll")                                                   \
            for (int n = 0; n < 2; ++n)                                         \
                _Pragma("unroll")                                               \
                for (int qs = 0; qs < 2; ++qs)                                  \
                    _Pragma("unroll")                                           \
                    for (int r = 0; r < 4; ++r)                                 \
                        if (kq + n*16 + r > (Q0) + qs*16 + l16)                 \
                            s[n][qs][r] = -1e30f;                               \
        }                                                                       \
        uint2 pck[2][2];                                                        \
        _Pragma("unroll")                                                       \
        for (int n = 0; n < 2; ++n)                                             \
            _Pragma("unroll")                                                   \
            for (int qs = 0; qs < 2; ++qs) {                                    \
                const float p0 = exp2f(s[n][qs][0]);                            \
                const float p1 = exp2f(s[n][qs][1]);                            \
                const float p2 = exp2f(s[n][qs][2]);                            \
                const float p3 = exp2f(s[n][qs][3]);                            \
                LST[qs] += (p0 + p1) + (p2 + p3);                               \
                pck[n][qs].x = pack2bf(p0, p1);                                 \
                pck[n][qs].y = pack2bf(p2, p3);                                 \
            }                                                                   \
        _Pragma("unroll")                                                       \
        for (int qs = 0; qs < 2; ++qs) {                                        \
            u32x4 pw = {pck[0][qs].x, pck[0][qs].y, pck[1][qs].x, pck[1][qs].y};\
            const bf16x8 ap = __builtin_bit_cast(bf16x8, pw);                   \
            _Pragma("unroll")                                                   \
            for (int dt = 0; dt < 4; ++dt)                                      \
                OACC[qs][dt] = __builtin_amdgcn_mfma_f32_16x16x32_bf16(         \
                    ap, bv[dt], OACC[qs][dt], 0, 0, 0);                         \
        }                                                                       \
    } while (0)

    for (int kt = 0; kt < nkth; ++kt) {
        __syncthreads();   // prev consumers done with Ks/Vt

        const unsigned short* ksrc = Kb + hbase + (size_t)kt * 128 * HEAD;
        #pragma unroll
        for (int ii = 0; ii < 4; ++ii)
            async_copy16(Ks + ii*2048 + tid*8,
                         ksrc + (size_t)(ii*32 + krow) * 64 + kchunk);
        #pragma unroll
        for (int ii = 0; ii < 4; ++ii)
            async_copy16(Vt + ii*2048 + tid*8,
                         VT + hbase + (size_t)(ii*16 + vrow) * TT + kt*128 + vchunk);
        asm volatile("s_waitcnt vmcnt(0)" ::: "memory");
        __syncthreads();

        // shared K fragments (wave's 32-k slice) and V fragments
        bf16x8 ak[2][2];
        #pragma unroll
        for (int kc2 = 0; kc2 < 2; ++kc2) {
            const int pos = ((kc2*4 + quad) ^ (l16 & 7)) * 8;
            #pragma unroll
            for (int n = 0; n < 2; ++n)
                ak[kc2][n] = *(const bf16x8*)(Ks + (wave*32 + n*16 + l16)*64 + pos);
        }
        bf16x8 bv[4];
        #pragma unroll
        for (int dt = 0; dt < 4; ++dt) {
            const unsigned short* vr = Vt + (dt*16 + l16)*128;
            const int c1 = ((g1     ^ l16) * 8) + (quad & 1) * 4;
            const int c2 = (((g1+2) ^ l16) * 8) + (quad & 1) * 4;
            const uint2 lo = *(const uint2*)(vr + c1);
            const uint2 hi = *(const uint2*)(vr + c2);
            u32x4 vv = {lo.x, lo.y, hi.x, hi.y};
            bv[dt] = __builtin_bit_cast(bf16x8, vv);
        }

        TILE_COMPUTE(qregh, oacch, lsth, q0h, (kt == nkth - 1), kt);
        if (kt < nktl)
            TILE_COMPUTE(qregl, oaccl, lstl, q0l, (kt == nktl - 1), kt);
    }
    #undef TILE_COMPUTE

    // cross-quad reduce l for both tiles
    #pragma unroll
    for (int qs = 0; qs < 2; ++qs) {
        lstl[qs] += __shfl_xor(lstl[qs], 16);
        lstl[qs] += __shfl_xor(lstl[qs], 32);
        lsth[qs] += __shfl_xor(lsth[qs], 16);
        lsth[qs] += __shfl_xor(lsth[qs], 32);
    }

    // ---- two combines via LDS (aliases Ks/Vt) + epilogue ----
    #define COMBINE(OACC, LST, Q0)                                              \
    do {                                                                        \
        float* O1 = (float*)Ks;                                                 \
        float* O2 = (float*)Ks + 2048;                                          \
        float* O3 = (float*)Vt;                                                 \
        float* Lb = (float*)Vt + 2048;                                          \
        __syncthreads();                                                        \
        if (wave != 0) {                                                        \
            float* ob = (wave == 1) ? O1 : (wave == 2) ? O2 : O3;               \
            _Pragma("unroll")                                                   \
            for (int qs = 0; qs < 2; ++qs)                                      \
                _Pragma("unroll")                                               \
                for (int dt = 0; dt < 4; ++dt)                                  \
                    _Pragma("unroll")                                           \
                    for (int r = 0; r < 4; ++r)                                 \
                        ob[(qs*16 + quad*4 + r)*64 + dt*16 + l16] = OACC[qs][dt][r]; \
            if (lane < 16) {                                                    \
                Lb[(wave-1)*32 + l16]      = LST[0];                            \
                Lb[(wave-1)*32 + 16 + l16] = LST[1];                            \
            }                                                                   \
        }                                                                       \
        __syncthreads();                                                        \
        if (wave == 0) {                                                        \
            float linv[2], lr[2][4];                                            \
            _Pragma("unroll")                                                   \
            for (int qs = 0; qs < 2; ++qs) {                                    \
                const float lt = LST[qs] + Lb[qs*16 + l16] + Lb[32 + qs*16 + l16] \
                                         + Lb[64 + qs*16 + l16];                \
                linv[qs] = 1.0f / lt;                                           \
            }                                                                   \
            _Pragma("unroll")                                                   \
            for (int qs = 0; qs < 2; ++qs)                                      \
                _Pragma("unroll")                                               \
                for (int r = 0; r < 4; ++r)                                     \
                    lr[qs][r] = __shfl(linv[qs], quad*4 + r);                   \
            const int b = bh / NHEADS, h = bh % NHEADS;                         \
            _Pragma("unroll")                                                   \
            for (int qs = 0; qs < 2; ++qs)                                      \
                _Pragma("unroll")                                               \
                for (int r = 0; r < 4; ++r) {                                   \
                    const int m = b * TT + (Q0) + qs*16 + quad*4 + r;           \
                    unsigned short* dst = Ob + (size_t)m * D_MODEL + h*HEAD;    \
                    _Pragma("unroll")                                           \
                    for (int dt = 0; dt < 4; ++dt) {                            \
                        const int idx = (qs*16 + quad*4 + r)*64 + dt*16 + l16;  \
                        const float v = OACC[qs][dt][r] + O1[idx] + O2[idx] + O3[idx]; \
                        dst[dt*16 + l16] = f2bf(v * lr[qs][r]);                 \
                    }                                                           \
                }                                                               \
        }                                                                       \
    } while (0)

    COMBINE(oaccl, lstl, q0l);
    COMBINE(oacch, lsth, q0h);
    #undef COMBINE
}

// ---------------------------------------------------------------------------
extern "C" void kernel_launch(void* const* d_in, const int* in_sizes, int n_in,
                              void* d_out, int out_size, void* d_ws, size_t ws_size,
                              hipStream_t stream) {
    const float* x  = (const float*)d_in[0];
    const float* W1 = (const float*)d_in[1];
    const float* b1 = (const float*)d_in[2];
    const float* W2 = (const float*)d_in[3];
    const float* b2 = (const float*)d_in[4];
    float* out = (float*)d_out;

    unsigned short* ws = (unsigned short*)d_ws;
    unsigned short* xb  = ws;                                   // 4096*768
    unsigned short* w1b = xb  + (size_t)NX;                     // 2304*768
    unsigned short* w2b = w1b + (size_t)NW1;                    // 768*768
    unsigned short* Qb  = w2b + (size_t)NW2;                    // 24*2048*64
    unsigned short* Kb  = Qb + (size_t)BB*NHEADS*TT*HEAD;
    unsigned short* VT  = Kb + (size_t)BB*NHEADS*TT*HEAD;       // (b,h,d,t)
    unsigned short* Ob  = VT + (size_t)BB*NHEADS*TT*HEAD;       // 4096*768

    prep<<<((NX + NW1 + NW2)/4 + 255)/256, 256, 0, stream>>>(
        x, W1, W2, xb, w1b, w2b);

    gemm1<<<768, 256, 0, stream>>>(
        xb, w1b, b1, KDIM, Qb, Kb, VT);

    attn<<<dim3(32, BB*NHEADS), 256, 0, stream>>>(Qb, Kb, VT, Ob);

    gemm2<<<512, 256, 0, stream>>>(
        Ob, w2b, b2, KDIM, out);
}